// Round 7
// baseline (672.248 us; speedup 1.0000x reference)
//
#include <hip/hip_runtime.h>
#include <hip/hip_bf16.h>

#define DEV __device__ __forceinline__

typedef unsigned short u16;
typedef unsigned int u32;
typedef __attribute__((ext_vector_type(8))) short short8;
typedef __attribute__((ext_vector_type(4))) float f32x4;
typedef __attribute__((ext_vector_type(16))) float f32x16;

static constexpr int Bb = 2, Ss = 2048, Hh = 4096, NQ = 32, NKV = 8, Dd = 128;
static constexpr int Mm = Bb * Ss; // 4096

DEV u16 f2bf(float f) {
    u32 u = __float_as_uint(f);
    u32 r = (u + 0x7fffu + ((u >> 16) & 1u)) >> 16;
    return (u16)r;
}
DEV float bf2f(u16 b) { return __uint_as_float((u32)b << 16); }
DEV u32 cvtpk(float lo, float hi) { // dst.lo=bf16(lo), dst.hi=bf16(hi)
    u32 r;
    asm("v_cvt_pk_bf16_f32 %0, %1, %2" : "=v"(r) : "v"(lo), "v"(hi));
    return r;
}

// ---------------- elementwise f32 -> bf16 cast ----------------
__global__ void k_cast(const float4* __restrict__ in, ushort4* __restrict__ out, int n4) {
    int i = blockIdx.x * 256 + threadIdx.x;
    if (i < n4) {
        float4 v = in[i];
        ushort4 o;
        o.x = f2bf(v.x); o.y = f2bf(v.y); o.z = f2bf(v.z); o.w = f2bf(v.w);
        out[i] = o;
    }
}

// ---------------- transpose + cast: in (R,C) f32 -> out (C,R) bf16 ----------------
__global__ void k_transpose(const float* __restrict__ in, u16* __restrict__ out, int R, int C) {
    __shared__ float t[32][33];
    int lx = threadIdx.x & 31, ly = threadIdx.x >> 5; // 32 x 8
    long tc = (long)blockIdx.x * 32, tr = (long)blockIdx.y * 32;
    #pragma unroll
    for (int i = 0; i < 32; i += 8) t[ly + i][lx] = in[(tr + ly + i) * C + tc + lx];
    __syncthreads();
    #pragma unroll
    for (int i = 0; i < 32; i += 8) out[(tc + ly + i) * R + tr + lx] = f2bf(t[lx][ly + i]);
}

DEV void gld16(const void* g, void* l) {
    __builtin_amdgcn_global_load_lds((const __attribute__((address_space(1))) void*)g,
                                     (__attribute__((address_space(3))) void*)l, 16, 0, 0);
}

#define FENCE asm volatile("" ::: "memory")

// ---------------- 256^2-tile 8-wave 4-phase GEMM (T2+T3+T4+T5) ----------------
template <int MODE>
__global__ __launch_bounds__(512) void k_gemm256(const u16* __restrict__ A, const u16* __restrict__ BT,
                                                 void* __restrict__ Cp, int M, int N, int K) {
    __shared__ u16 S[2][32768];
    const int tid = threadIdx.x, lane = tid & 63, wid = tid >> 6;
    const int wr = wid >> 2, wc = wid & 3;
    const long m0 = (long)blockIdx.y * 256, n0 = (long)blockIdx.x * 256;
    const int r15 = lane & 15;
    const int cch0 = 8 * ((lane >> 4) ^ (r15 & 7));

    const u16 *pA[4], *pB[4];
    {
        int srow = wid * 8 + (lane >> 3);
        int scol = 8 * ((lane & 7) ^ (lane >> 3));
        #pragma unroll
        for (int j = 0; j < 4; j++) {
            pA[j] = A + (m0 + j * 64 + srow) * (long)K + scol;
            pB[j] = BT + (n0 + j * 64 + srow) * (long)K + scol;
        }
    }

    f32x4 acc[8][4];
    #pragma unroll
    for (int i = 0; i < 8; i++)
        #pragma unroll
        for (int j = 0; j < 4; j++) acc[i][j] = f32x4{0.f, 0.f, 0.f, 0.f};

    const int NT = K / 64;
    auto STAGE_A = [&](int t) {
        int tb = t & 1; long ko = (long)t * 64;
        #pragma unroll
        for (int j = 0; j < 4; j++) gld16(pA[j] + ko, (void*)&S[tb][j * 4096 + wid * 512]);
    };
    auto STAGE_B = [&](int t) {
        int tb = t & 1; long ko = (long)t * 64;
        #pragma unroll
        for (int j = 0; j < 4; j++) gld16(pB[j] + ko, (void*)&S[tb][16384 + j * 4096 + wid * 512]);
    };

    const int aro = wr * 8192 + r15 * 64 + cch0;
    const int bro = 16384 + (wc >> 1) * 8192 + (wc & 1) * 4096 + r15 * 64 + cch0;

    STAGE_B(0); STAGE_A(0); STAGE_B(1); STAGE_A(1);
    asm volatile("s_waitcnt vmcnt(8)" ::: "memory");
    FENCE; __builtin_amdgcn_s_barrier(); FENCE;

    short8 af[4][2], b01[2][2], b23[2][2];
    for (int kt = 0; kt < NT; ++kt) {
        const u16* Sb = S[kt & 1];
        // phase 0
        #pragma unroll
        for (int m = 0; m < 4; m++) {
            af[m][0] = *(const short8*)&Sb[aro + m * 1024];
            af[m][1] = *(const short8*)&Sb[(aro + m * 1024) ^ 32];
        }
        #pragma unroll
        for (int n = 0; n < 2; n++) {
            b01[n][0] = *(const short8*)&Sb[bro + n * 1024];
            b01[n][1] = *(const short8*)&Sb[(bro + n * 1024) ^ 32];
        }
        FENCE; __builtin_amdgcn_s_barrier(); FENCE;
        __builtin_amdgcn_s_setprio(1);
        #pragma unroll
        for (int m = 0; m < 4; m++)
            #pragma unroll
            for (int n = 0; n < 2; n++) {
                acc[m][n] = __builtin_amdgcn_mfma_f32_16x16x32_bf16(af[m][0], b01[n][0], acc[m][n], 0, 0, 0);
                acc[m][n] = __builtin_amdgcn_mfma_f32_16x16x32_bf16(af[m][1], b01[n][1], acc[m][n], 0, 0, 0);
            }
        __builtin_amdgcn_s_setprio(0);
        FENCE; __builtin_amdgcn_s_barrier(); FENCE;
        // phase 1
        #pragma unroll
        for (int n = 0; n < 2; n++) {
            b23[n][0] = *(const short8*)&Sb[bro + (n + 2) * 1024];
            b23[n][1] = *(const short8*)&Sb[(bro + (n + 2) * 1024) ^ 32];
        }
        FENCE; __builtin_amdgcn_s_barrier(); FENCE;
        __builtin_amdgcn_s_setprio(1);
        #pragma unroll
        for (int m = 0; m < 4; m++)
            #pragma unroll
            for (int n = 0; n < 2; n++) {
                acc[m][n + 2] = __builtin_amdgcn_mfma_f32_16x16x32_bf16(af[m][0], b23[n][0], acc[m][n + 2], 0, 0, 0);
                acc[m][n + 2] = __builtin_amdgcn_mfma_f32_16x16x32_bf16(af[m][1], b23[n][1], acc[m][n + 2], 0, 0, 0);
            }
        __builtin_amdgcn_s_setprio(0);
        FENCE; __builtin_amdgcn_s_barrier(); FENCE;
        // phase 2
        if (kt + 2 < NT) STAGE_B(kt + 2);
        #pragma unroll
        for (int m = 0; m < 4; m++) {
            af[m][0] = *(const short8*)&Sb[aro + (m + 4) * 1024];
            af[m][1] = *(const short8*)&Sb[(aro + (m + 4) * 1024) ^ 32];
        }
        FENCE; __builtin_amdgcn_s_barrier(); FENCE;
        __builtin_amdgcn_s_setprio(1);
        #pragma unroll
        for (int m = 0; m < 4; m++)
            #pragma unroll
            for (int n = 0; n < 2; n++) {
                acc[m + 4][n] = __builtin_amdgcn_mfma_f32_16x16x32_bf16(af[m][0], b01[n][0], acc[m + 4][n], 0, 0, 0);
                acc[m + 4][n] = __builtin_amdgcn_mfma_f32_16x16x32_bf16(af[m][1], b01[n][1], acc[m + 4][n], 0, 0, 0);
            }
        __builtin_amdgcn_s_setprio(0);
        FENCE; __builtin_amdgcn_s_barrier(); FENCE;
        // phase 3
        if (kt + 2 < NT) {
            STAGE_A(kt + 2);
            asm volatile("s_waitcnt vmcnt(8)" ::: "memory");
        } else {
            asm volatile("s_waitcnt vmcnt(0)" ::: "memory");
        }
        FENCE; __builtin_amdgcn_s_barrier(); FENCE;
        __builtin_amdgcn_s_setprio(1);
        #pragma unroll
        for (int m = 0; m < 4; m++)
            #pragma unroll
            for (int n = 0; n < 2; n++) {
                acc[m + 4][n + 2] = __builtin_amdgcn_mfma_f32_16x16x32_bf16(af[m][0], b23[n][0], acc[m + 4][n + 2], 0, 0, 0);
                acc[m + 4][n + 2] = __builtin_amdgcn_mfma_f32_16x16x32_bf16(af[m][1], b23[n][1], acc[m + 4][n + 2], 0, 0, 0);
            }
        __builtin_amdgcn_s_setprio(0);
        FENCE; __builtin_amdgcn_s_barrier(); FENCE;
    }

    const int rq = (lane >> 4) * 4;
    #pragma unroll
    for (int m = 0; m < 8; m++) {
        #pragma unroll
        for (int n = 0; n < 4; n++) {
            long row0 = m0 + wr * 128 + m * 16 + rq;
            long col = n0 + wc * 64 + n * 16 + r15;
            if (MODE == 0) {
                float* Cf = (float*)Cp;
                #pragma unroll
                for (int i = 0; i < 4; i++) Cf[(row0 + i) * N + col] = acc[m][n][i];
            } else {
                u16* Cb = (u16*)Cp;
                #pragma unroll
                for (int i = 0; i < 4; i++) Cb[(row0 + i) * N + col] = f2bf(acc[m][n][i]);
            }
        }
    }
}

// ---------------- 128^2 GEMM (kept for N=1024 K/V projections) ----------------
template <int MODE>
__global__ __launch_bounds__(256) void k_gemm_bt(const u16* __restrict__ A, const u16* __restrict__ BT,
                                                 void* __restrict__ Cp, int M, int N, int K) {
    __shared__ u16 As[4096];
    __shared__ u16 Bs[4096];
    int tid = threadIdx.x, lane = tid & 63, wid = tid >> 6;
    int wr = wid >> 1, wc = wid & 1;
    long m0 = (long)blockIdx.y * 128, n0 = (long)blockIdx.x * 128;
    const f32x4 fz = {0.f, 0.f, 0.f, 0.f};
    f32x4 acc[4][4];
    #pragma unroll
    for (int i = 0; i < 4; i++)
        #pragma unroll
        for (int j = 0; j < 4; j++) acc[i][j] = fz;

    const u16* gA = A + (m0 + (tid >> 2)) * K + (tid & 3) * 8;
    const u16* gB = BT + (n0 + (tid >> 2)) * K + (tid & 3) * 8;
    u16* lA0 = As + wid * 512;
    u16* lA1 = As + 2048 + wid * 512;
    u16* lB0 = Bs + wid * 512;
    u16* lB1 = Bs + 2048 + wid * 512;
    int r15 = lane & 15, khalf = (lane >> 4) * 8;
    long rowoff = (long)64 * K;

    for (int kt = 0; kt < K; kt += 32) {
        gld16(gA + kt, lA0);
        gld16(gA + kt + rowoff, lA1);
        gld16(gB + kt, lB0);
        gld16(gB + kt + rowoff, lB1);
        __syncthreads();
        short8 av[4], bv[4];
        #pragma unroll
        for (int f = 0; f < 4; f++) {
            av[f] = *(const short8*)&As[(wr * 64 + f * 16 + r15) * 32 + khalf];
            bv[f] = *(const short8*)&Bs[(wc * 64 + f * 16 + r15) * 32 + khalf];
        }
        #pragma unroll
        for (int i = 0; i < 4; i++)
            #pragma unroll
            for (int j = 0; j < 4; j++)
                acc[i][j] = __builtin_amdgcn_mfma_f32_16x16x32_bf16(av[i], bv[j], acc[i][j], 0, 0, 0);
        __syncthreads();
    }

    int rq = (lane >> 4) * 4;
    #pragma unroll
    for (int mf = 0; mf < 4; mf++) {
        #pragma unroll
        for (int nf = 0; nf < 4; nf++) {
            long row0 = m0 + wr * 64 + mf * 16 + rq;
            long col = n0 + wc * 64 + nf * 16 + r15;
            if (MODE == 1) {
                u16* Cb = (u16*)Cp;
                ushort4 pk;
                pk.x = f2bf(acc[mf][nf][0]);
                pk.y = f2bf(acc[mf][nf][1]);
                pk.z = f2bf(acc[mf][nf][2]);
                pk.w = f2bf(acc[mf][nf][3]);
                *(ushort4*)&Cb[col * M + row0] = pk;
            } else {
                u16* Cb = (u16*)Cp;
                #pragma unroll
                for (int i = 0; i < 4; i++) Cb[(row0 + i) * N + col] = f2bf(acc[mf][nf][i]);
            }
        }
    }
}

// ---------------- fused RMSNorm + RoPE, bf16 in-place ----------------
__global__ __launch_bounds__(256) void k_normrope(u16* __restrict__ buf,
                                                  const float* __restrict__ w, int NH, float oscale) {
    int row = blockIdx.x * 4 + (threadIdx.x >> 6);
    int lane = threadIdx.x & 63;
    long base = (long)row * 128;
    float x1 = bf2f(buf[base + lane]), x2 = bf2f(buf[base + lane + 64]);
    float ss = x1 * x1 + x2 * x2;
    #pragma unroll
    for (int m = 1; m < 64; m <<= 1) ss += __shfl_xor(ss, m);
    float r = rsqrtf(ss * (1.f / 128.f) + 1e-6f);
    float n1 = x1 * r * w[lane], n2 = x2 * r * w[lane + 64];
    int pos = (row / NH) % Ss;
    float invf = exp2f((float)lane * (-19.931568569324174f / 64.f));
    float ang = (float)pos * invf;
    float c = cosf(ang), sn = sinf(ang);
    buf[base + lane] = f2bf((n1 * c - n2 * sn) * oscale);
    buf[base + lane + 64] = f2bf((n2 * c + n1 * sn) * oscale);
}

// ---------------- flash attention, single q-tile/wave, 32-key tiles, LPT order ----------------
// Block bx in [0,64): q0 = (63-bx)*32 (longest blocks dispatched first -> LPT packing).
// 4 waves = 4 q-heads of kv-head blockIdx.y. LDS 32KB (2 x (8KB K + 8KB V)) -> 3 blocks/CU;
// single-tile state (~160 VGPR) -> 3 waves/SIMD. 12 waves/CU vs round-5's 8.
// KT: [32 kv][128 d], 16B-chunk el-xor ((kv&15)<<3), conflict-free.
// VT: [128 d][32 k], 16B-chunk el-xor (d&3) -> 2-way within LDS cycle groups (free).
__global__ __launch_bounds__(256, 3) void k_attn(const u16* __restrict__ Q, const u16* __restrict__ Kb,
                                                 const u16* __restrict__ Vg, u16* __restrict__ O) {
    __shared__ u16 KT[2][32 * 128];
    __shared__ u16 VT[2][128 * 32];
    int tid = threadIdx.x, lane = tid & 63, wid = tid >> 6;
    int b = blockIdx.z;
    int hk = blockIdx.y;
    int h = hk * 4 + wid;          // each wave owns one q-head of this kv-head
    int q0 = (63 - blockIdx.x) * 32; // LPT: longest first
    int c31 = lane & 31, hi5 = lane >> 5;
    int ql = q0 + c31;
    int kx16 = (c31 & 15) << 3;    // KT read xor
    int vx = (c31 & 3);            // VT read xor (4 chunks per 64B row)

    // Q fragments (B-operand): lane holds Q[q=c31][d = 16c + hi5*8 + j]
    const u16* qrow = Q + ((long)(b * Ss + ql) * NQ + h) * Dd + hi5 * 8;
    short8 qf[8];
    #pragma unroll
    for (int c = 0; c < 8; c++) qf[c] = *(const short8*)(qrow + c * 16);

    // staging source pointers (per-lane, inverse-swizzled). wave stages instrs i = wid*2 + ii.
    const u16* kg[2];
    const u16* vg[2];
    #pragma unroll
    for (int ii = 0; ii < 2; ii++) {
        int i = wid * 2 + ii;
        int r = i * 4 + (lane >> 4);                 // kv row 0..31
        kg[ii] = Kb + ((long)(b * Ss + r) * NKV + hk) * Dd + 8 * ((lane & 15) ^ (r & 15));
        int d = i * 16 + (lane >> 2);                // d row 0..127
        vg[ii] = Vg + (long)(hk * Dd + d) * Mm + (long)b * Ss + 8 * ((lane & 3) ^ ((lane >> 2) & 3));
    }

    f32x16 oa[4];
    #pragma unroll
    for (int f = 0; f < 4; f++)
        #pragma unroll
        for (int r = 0; r < 16; r++) oa[f][r] = 0.f;
    float mrun = -INFINITY, lrun = 0.f;

    const long kadv = (long)32 * NKV * Dd; // K rows advance per 32-key tile
    int nt = q0 / 32 + 1;
    int cur = 0;

    // prologue: stage tile 0 into buf 0
    #pragma unroll
    for (int ii = 0; ii < 2; ii++) {
        int i = wid * 2 + ii;
        gld16(kg[ii], &KT[0][i * 512]);
        gld16(vg[ii], &VT[0][i * 512]);
    }
    __syncthreads();

    for (int t = 0; t < nt; ++t) {
        if (t + 1 < nt) { // prefetch next 32-key tile into other buffer
            long ko = (long)(t + 1) * kadv;
            int vo = (t + 1) * 32;
            #pragma unroll
            for (int ii = 0; ii < 2; ii++) {
                int i = wid * 2 + ii;
                gld16(kg[ii] + ko, &KT[cur ^ 1][i * 512]);
                gld16(vg[ii] + vo, &VT[cur ^ 1][i * 512]);
            }
        }
        int k0 = t * 32;
        // S^T(32k x 32q) = K(32 x D) @ Q^T(D x 32), K from LDS (swizzled)
        f32x16 st;
        #pragma unroll
        for (int r = 0; r < 16; r++) st[r] = 0.f;
        __builtin_amdgcn_s_setprio(1);
        #pragma unroll
        for (int c = 0; c < 8; c++) {
            short8 kf = *(const short8*)&KT[cur][c31 * 128 + ((c * 16 + hi5 * 8) ^ kx16)];
            st = __builtin_amdgcn_mfma_f32_32x32x16_bf16(kf, qf[c], st, 0, 0, 0);
        }
        __builtin_amdgcn_s_setprio(0);
        // mask only the diagonal tile (t == nt-1); key of reg r: k0 + (r&3) + 8*(r>>2) + 4*hi5
        float p[16];
        if (t == nt - 1) {
            #pragma unroll
            for (int r = 0; r < 16; r++) {
                int kidx = k0 + (r & 3) + 8 * (r >> 2) + 4 * hi5;
                p[r] = (kidx > ql) ? -INFINITY : st[r];
            }
        } else {
            #pragma unroll
            for (int r = 0; r < 16; r++) p[r] = st[r];
        }
        // pairwise max tree (depth 4)
        float m8[8], m4[4];
        #pragma unroll
        for (int r = 0; r < 8; r++) m8[r] = fmaxf(p[2 * r], p[2 * r + 1]);
        #pragma unroll
        for (int r = 0; r < 4; r++) m4[r] = fmaxf(m8[2 * r], m8[2 * r + 1]);
        float pmax = fmaxf(fmaxf(m4[0], m4[1]), fmaxf(m4[2], m4[3]));
        pmax = fmaxf(pmax, __shfl_xor(pmax, 32));
        // defer-max: only rescale when max grew by > 8 (exp2 domain, P <= 256)
        if (!__all(pmax - mrun <= 8.f)) {
            float mnew = fmaxf(mrun, pmax);
            float sc = __builtin_amdgcn_exp2f(mrun - mnew);
            lrun *= sc;
            #pragma unroll
            for (int f = 0; f < 4; f++)
                #pragma unroll
                for (int r = 0; r < 16; r++) oa[f][r] *= sc;
            mrun = mnew;
        }
        #pragma unroll
        for (int r = 0; r < 16; r++) p[r] = __builtin_amdgcn_exp2f(p[r] - mrun);
        // pairwise sum tree
        float s8[8], s4[4];
        #pragma unroll
        for (int r = 0; r < 8; r++) s8[r] = p[2 * r] + p[2 * r + 1];
        #pragma unroll
        for (int r = 0; r < 4; r++) s4[r] = s8[2 * r] + s8[2 * r + 1];
        float ls = (s4[0] + s4[1]) + (s4[2] + s4[3]);
        ls += __shfl_xor(ls, 32);
        lrun += ls;

        // P^T -> B-operand relayout: cvt_pk pairs + half-swap via shfl_xor(32)
        u32 w0 = cvtpk(p[0], p[1]), w1 = cvtpk(p[2], p[3]);
        u32 w2 = cvtpk(p[4], p[5]), w3 = cvtpk(p[6], p[7]);
        u32 w4 = cvtpk(p[8], p[9]), w5 = cvtpk(p[10], p[11]);
        u32 w6 = cvtpk(p[12], p[13]), w7 = cvtpk(p[14], p[15]);
        u32 x0 = (u32)__shfl_xor((int)w0, 32), x1 = (u32)__shfl_xor((int)w1, 32);
        u32 x2 = (u32)__shfl_xor((int)w2, 32), x3 = (u32)__shfl_xor((int)w3, 32);
        u32 x4 = (u32)__shfl_xor((int)w4, 32), x5 = (u32)__shfl_xor((int)w5, 32);
        u32 x6 = (u32)__shfl_xor((int)w6, 32), x7 = (u32)__shfl_xor((int)w7, 32);
        union { u32 u[4]; short8 s; } pb0, pb1;
        if (hi5) {
            pb0.u[0] = x2; pb0.u[1] = x3; pb0.u[2] = w2; pb0.u[3] = w3;
            pb1.u[0] = x6; pb1.u[1] = x7; pb1.u[2] = w6; pb1.u[3] = w7;
        } else {
            pb0.u[0] = w0; pb0.u[1] = w1; pb0.u[2] = x0; pb0.u[3] = x1;
            pb1.u[0] = w4; pb1.u[1] = w5; pb1.u[2] = x4; pb1.u[3] = x5;
        }
        // O^T(D x 32q) += V^T(D x 32k) @ P^T(32k x 32q), V^T from LDS (swizzled)
        __builtin_amdgcn_s_setprio(1);
        #pragma unroll
        for (int f = 0; f < 4; f++) {
            int d = 32 * f + c31;
            const u16* vrow = &VT[cur][d * 32];
            short8 v0 = *(const short8*)&vrow[8 * (hi5 ^ vx)];
            short8 v1 = *(const short8*)&vrow[8 * ((2 + hi5) ^ vx)];
            oa[f] = __builtin_amdgcn_mfma_f32_32x32x16_bf16(v0, pb0.s, oa[f], 0, 0, 0);
            oa[f] = __builtin_amdgcn_mfma_f32_32x32x16_bf16(v1, pb1.s, oa[f], 0, 0, 0);
        }
        __builtin_amdgcn_s_setprio(0);
        __syncthreads(); // drains prefetch vmcnt + protects buffer reuse
        cur ^= 1;
    }

    float linv = 1.f / lrun;
    u16* orow = O + ((long)(b * Ss + ql) * NQ + h) * Dd;
    #pragma unroll
    for (int f = 0; f < 4; f++) {
        #pragma unroll
        for (int rq = 0; rq < 4; rq++) {
            int dbase = 32 * f + 8 * rq + 4 * hi5;
            union { u32 u[2]; ushort4 v; } pk;
            pk.u[0] = cvtpk(oa[f][4 * rq + 0] * linv, oa[f][4 * rq + 1] * linv);
            pk.u[1] = cvtpk(oa[f][4 * rq + 2] * linv, oa[f][4 * rq + 3] * linv);
            *(ushort4*)(orow + dbase) = pk.v;
        }
    }
}

// ---------------- launch ----------------
// Workspace layout (bytes), peak 112 MB:
//   [  0, 32M): xb  = x bf16 (Mm x Hh)            -- dead after V GEMM, reused as ao
//   [ 32, 64M): W   = transposed-weight scratch    -- wq^T / wk^T / wv^T / wo^T in turn
//   [ 64, 96M): qb  = q bf16 (Mm x NQ*D), normrope in-place
//   [ 96,104M): kb  = k bf16 (Mm x NKV*D), normrope in-place
//   [104,112M): vt  = V^T bf16 (NKV*D x Mm)
extern "C" void kernel_launch(void* const* d_in, const int* in_sizes, int n_in,
                              void* d_out, int out_size, void* d_ws, size_t ws_size,
                              hipStream_t stream) {
    (void)in_sizes; (void)n_in; (void)out_size; (void)ws_size;
    const float* x = (const float*)d_in[0];
    const float* wq = (const float*)d_in[1];
    const float* wk = (const float*)d_in[2];
    const float* wv = (const float*)d_in[3];
    const float* wo = (const float*)d_in[4];
    const float* qnw = (const float*)d_in[5];
    const float* knw = (const float*)d_in[6];

    char* ws = (char*)d_ws;
    const size_t MB = 1024 * 1024;
    u16* xb = (u16*)(ws);
    u16* W  = (u16*)(ws + 32 * MB);
    u16* qb = (u16*)(ws + 64 * MB);
    u16* kb = (u16*)(ws + 96 * MB);
    u16* vt = (u16*)(ws + 104 * MB);
    u16* ao = xb; // x bf16 dead after V GEMM; attention output reuses it

    int n4 = Mm * Hh / 4;
    k_cast<<<n4 / 256, 256, 0, stream>>>((const float4*)x, (ushort4*)xb, n4);

    // Q path — scale folds attention D^-0.5 AND log2(e) for exp2-domain softmax
    k_transpose<<<dim3(Hh / 32, Hh / 32), 256, 0, stream>>>(wq, W, Hh, Hh);
    k_gemm256<2><<<dim3(Hh / 256, Mm / 256), 512, 0, stream>>>(xb, W, qb, Mm, Hh, Hh);
    k_normrope<<<(Mm * NQ) / 4, 256, 0, stream>>>(qb, qnw, NQ,
        (float)(0.08838834764831845 * 1.4426950408889634));

    // K path (N=1024: 128^2 kernel keeps the grid full)
    k_transpose<<<dim3((NKV * Dd) / 32, Hh / 32), 256, 0, stream>>>(wk, W, Hh, NKV * Dd);
    k_gemm_bt<2><<<dim3((NKV * Dd) / 128, Mm / 128), 256, 0, stream>>>(xb, W, kb, Mm, NKV * Dd, Hh);
    k_normrope<<<(Mm * NKV) / 4, 256, 0, stream>>>(kb, knw, NKV, 1.0f);

    // V path (writes V^T directly)
    k_transpose<<<dim3((NKV * Dd) / 32, Hh / 32), 256, 0, stream>>>(wv, W, Hh, NKV * Dd);
    k_gemm_bt<1><<<dim3((NKV * Dd) / 128, Mm / 128), 256, 0, stream>>>(xb, W, vt, Mm, NKV * Dd, Hh);

    // attention: 64 q-tiles (LPT order) x NKV x B, 4 q-heads per block
    k_attn<<<dim3(64, NKV, Bb), 256, 0, stream>>>(qb, kb, vt, ao);

    // output projection -> f32 d_out
    k_transpose<<<dim3(Hh / 32, Hh / 32), 256, 0, stream>>>(wo, W, Hh, Hh);
    k_gemm256<0><<<dim3(Hh / 256, Mm / 256), 512, 0, stream>>>(ao, W, d_out, Mm, Hh, NQ * Dd);
}

// Round 8
// 568.340 us; speedup vs baseline: 1.1828x; 1.1828x over previous
//
#include <hip/hip_runtime.h>
#include <hip/hip_bf16.h>

#define DEV __device__ __forceinline__

typedef unsigned short u16;
typedef unsigned int u32;
typedef __attribute__((ext_vector_type(8))) short short8;
typedef __attribute__((ext_vector_type(4))) float f32x4;
typedef __attribute__((ext_vector_type(16))) float f32x16;

static constexpr int Bb = 2, Ss = 2048, Hh = 4096, NQ = 32, NKV = 8, Dd = 128;
static constexpr int Mm = Bb * Ss; // 4096

DEV u16 f2bf(float f) {
    u32 u = __float_as_uint(f);
    u32 r = (u + 0x7fffu + ((u >> 16) & 1u)) >> 16;
    return (u16)r;
}
DEV float bf2f(u16 b) { return __uint_as_float((u32)b << 16); }
DEV u32 cvtpk(float lo, float hi) { // dst.lo=bf16(lo), dst.hi=bf16(hi)
    u32 r;
    asm("v_cvt_pk_bf16_f32 %0, %1, %2" : "=v"(r) : "v"(lo), "v"(hi));
    return r;
}

// ---------------- elementwise f32 -> bf16 cast ----------------
__global__ void k_cast(const float4* __restrict__ in, ushort4* __restrict__ out, int n4) {
    int i = blockIdx.x * 256 + threadIdx.x;
    if (i < n4) {
        float4 v = in[i];
        ushort4 o;
        o.x = f2bf(v.x); o.y = f2bf(v.y); o.z = f2bf(v.z); o.w = f2bf(v.w);
        out[i] = o;
    }
}

// ---------------- transpose + cast: in (R,C) f32 -> out (C,R) bf16 ----------------
__global__ void k_transpose(const float* __restrict__ in, u16* __restrict__ out, int R, int C) {
    __shared__ float t[32][33];
    int lx = threadIdx.x & 31, ly = threadIdx.x >> 5; // 32 x 8
    long tc = (long)blockIdx.x * 32, tr = (long)blockIdx.y * 32;
    #pragma unroll
    for (int i = 0; i < 32; i += 8) t[ly + i][lx] = in[(tr + ly + i) * C + tc + lx];
    __syncthreads();
    #pragma unroll
    for (int i = 0; i < 32; i += 8) out[(tc + ly + i) * R + tr + lx] = f2bf(t[lx][ly + i]);
}

DEV void gld16(const void* g, void* l) {
    __builtin_amdgcn_global_load_lds((const __attribute__((address_space(1))) void*)g,
                                     (__attribute__((address_space(3))) void*)l, 16, 0, 0);
}

#define FENCE asm volatile("" ::: "memory")

// ---------------- 256^2-tile 8-wave 4-phase GEMM (T2+T3+T4+T5) ----------------
// MODE 0: f32 C0 row-major (ld=N). MODE 2: bf16 C0 row-major (ld=N).
// MODE 3: fused QKV epilogue — blockIdx.x<16: q->C0 bf16 ld 4096; 16..19: k->C1 bf16 ld 1024;
//         20..23: v->C2 bf16 TRANSPOSED (C2[(col-5120)*Mm + row]). B rows from B0 (q) or B1 (k|v).
template <int MODE>
__global__ __launch_bounds__(512) void k_gemm256(const u16* __restrict__ A, const u16* __restrict__ B0,
                                                 const u16* __restrict__ B1, void* __restrict__ C0,
                                                 void* __restrict__ C1, void* __restrict__ C2,
                                                 int M, int N, int K) {
    __shared__ u16 S[2][32768];
    const int tid = threadIdx.x, lane = tid & 63, wid = tid >> 6;
    const int wr = wid >> 2, wc = wid & 3;
    const long m0 = (long)blockIdx.y * 256, n0 = (long)blockIdx.x * 256;
    const int r15 = lane & 15;
    const int cch0 = 8 * ((lane >> 4) ^ (r15 & 7));

    const u16* Bbase = B0;
    long nb0 = n0;
    if (MODE == 3 && blockIdx.x >= 16) { Bbase = B1; nb0 = n0 - 4096; }

    const u16 *pA[4], *pB[4];
    {
        int srow = wid * 8 + (lane >> 3);
        int scol = 8 * ((lane & 7) ^ (lane >> 3));
        #pragma unroll
        for (int j = 0; j < 4; j++) {
            pA[j] = A + (m0 + j * 64 + srow) * (long)K + scol;
            pB[j] = Bbase + (nb0 + j * 64 + srow) * (long)K + scol;
        }
    }

    f32x4 acc[8][4];
    #pragma unroll
    for (int i = 0; i < 8; i++)
        #pragma unroll
        for (int j = 0; j < 4; j++) acc[i][j] = f32x4{0.f, 0.f, 0.f, 0.f};

    const int NT = K / 64;
    auto STAGE_A = [&](int t) {
        int tb = t & 1; long ko = (long)t * 64;
        #pragma unroll
        for (int j = 0; j < 4; j++) gld16(pA[j] + ko, (void*)&S[tb][j * 4096 + wid * 512]);
    };
    auto STAGE_B = [&](int t) {
        int tb = t & 1; long ko = (long)t * 64;
        #pragma unroll
        for (int j = 0; j < 4; j++) gld16(pB[j] + ko, (void*)&S[tb][16384 + j * 4096 + wid * 512]);
    };

    const int aro = wr * 8192 + r15 * 64 + cch0;
    const int bro = 16384 + (wc >> 1) * 8192 + (wc & 1) * 4096 + r15 * 64 + cch0;

    STAGE_B(0); STAGE_A(0); STAGE_B(1); STAGE_A(1);
    asm volatile("s_waitcnt vmcnt(8)" ::: "memory");
    FENCE; __builtin_amdgcn_s_barrier(); FENCE;

    short8 af[4][2], b01[2][2], b23[2][2];
    for (int kt = 0; kt < NT; ++kt) {
        const u16* Sb = S[kt & 1];
        // phase 0
        #pragma unroll
        for (int m = 0; m < 4; m++) {
            af[m][0] = *(const short8*)&Sb[aro + m * 1024];
            af[m][1] = *(const short8*)&Sb[(aro + m * 1024) ^ 32];
        }
        #pragma unroll
        for (int n = 0; n < 2; n++) {
            b01[n][0] = *(const short8*)&Sb[bro + n * 1024];
            b01[n][1] = *(const short8*)&Sb[(bro + n * 1024) ^ 32];
        }
        FENCE; __builtin_amdgcn_s_barrier(); FENCE;
        __builtin_amdgcn_s_setprio(1);
        #pragma unroll
        for (int m = 0; m < 4; m++)
            #pragma unroll
            for (int n = 0; n < 2; n++) {
                acc[m][n] = __builtin_amdgcn_mfma_f32_16x16x32_bf16(af[m][0], b01[n][0], acc[m][n], 0, 0, 0);
                acc[m][n] = __builtin_amdgcn_mfma_f32_16x16x32_bf16(af[m][1], b01[n][1], acc[m][n], 0, 0, 0);
            }
        __builtin_amdgcn_s_setprio(0);
        FENCE; __builtin_amdgcn_s_barrier(); FENCE;
        // phase 1
        #pragma unroll
        for (int n = 0; n < 2; n++) {
            b23[n][0] = *(const short8*)&Sb[bro + (n + 2) * 1024];
            b23[n][1] = *(const short8*)&Sb[(bro + (n + 2) * 1024) ^ 32];
        }
        FENCE; __builtin_amdgcn_s_barrier(); FENCE;
        __builtin_amdgcn_s_setprio(1);
        #pragma unroll
        for (int m = 0; m < 4; m++)
            #pragma unroll
            for (int n = 0; n < 2; n++) {
                acc[m][n + 2] = __builtin_amdgcn_mfma_f32_16x16x32_bf16(af[m][0], b23[n][0], acc[m][n + 2], 0, 0, 0);
                acc[m][n + 2] = __builtin_amdgcn_mfma_f32_16x16x32_bf16(af[m][1], b23[n][1], acc[m][n + 2], 0, 0, 0);
            }
        __builtin_amdgcn_s_setprio(0);
        FENCE; __builtin_amdgcn_s_barrier(); FENCE;
        // phase 2
        if (kt + 2 < NT) STAGE_B(kt + 2);
        #pragma unroll
        for (int m = 0; m < 4; m++) {
            af[m][0] = *(const short8*)&Sb[aro + (m + 4) * 1024];
            af[m][1] = *(const short8*)&Sb[(aro + (m + 4) * 1024) ^ 32];
        }
        FENCE; __builtin_amdgcn_s_barrier(); FENCE;
        __builtin_amdgcn_s_setprio(1);
        #pragma unroll
        for (int m = 0; m < 4; m++)
            #pragma unroll
            for (int n = 0; n < 2; n++) {
                acc[m + 4][n] = __builtin_amdgcn_mfma_f32_16x16x32_bf16(af[m][0], b01[n][0], acc[m + 4][n], 0, 0, 0);
                acc[m + 4][n] = __builtin_amdgcn_mfma_f32_16x16x32_bf16(af[m][1], b01[n][1], acc[m + 4][n], 0, 0, 0);
            }
        __builtin_amdgcn_s_setprio(0);
        FENCE; __builtin_amdgcn_s_barrier(); FENCE;
        // phase 3
        if (kt + 2 < NT) {
            STAGE_A(kt + 2);
            asm volatile("s_waitcnt vmcnt(8)" ::: "memory");
        } else {
            asm volatile("s_waitcnt vmcnt(0)" ::: "memory");
        }
        FENCE; __builtin_amdgcn_s_barrier(); FENCE;
        __builtin_amdgcn_s_setprio(1);
        #pragma unroll
        for (int m = 0; m < 4; m++)
            #pragma unroll
            for (int n = 0; n < 2; n++) {
                acc[m + 4][n + 2] = __builtin_amdgcn_mfma_f32_16x16x32_bf16(af[m][0], b23[n][0], acc[m + 4][n + 2], 0, 0, 0);
                acc[m + 4][n + 2] = __builtin_amdgcn_mfma_f32_16x16x32_bf16(af[m][1], b23[n][1], acc[m + 4][n + 2], 0, 0, 0);
            }
        __builtin_amdgcn_s_setprio(0);
        FENCE; __builtin_amdgcn_s_barrier(); FENCE;
    }

    const int rq = (lane >> 4) * 4;
    #pragma unroll
    for (int m = 0; m < 8; m++) {
        #pragma unroll
        for (int n = 0; n < 4; n++) {
            long row0 = m0 + wr * 128 + m * 16 + rq;
            long col = n0 + wc * 64 + n * 16 + r15;
            if (MODE == 0) {
                float* Cf = (float*)C0;
                #pragma unroll
                for (int i = 0; i < 4; i++) Cf[(row0 + i) * N + col] = acc[m][n][i];
            } else if (MODE == 2) {
                u16* Cb = (u16*)C0;
                #pragma unroll
                for (int i = 0; i < 4; i++) Cb[(row0 + i) * N + col] = f2bf(acc[m][n][i]);
            } else { // MODE 3: fused QKV routing (block-uniform)
                if (blockIdx.x < 16) {
                    u16* Cb = (u16*)C0;
                    #pragma unroll
                    for (int i = 0; i < 4; i++) Cb[(row0 + i) * 4096 + col] = f2bf(acc[m][n][i]);
                } else if (blockIdx.x < 20) {
                    u16* Cb = (u16*)C1;
                    long cl = col - 4096;
                    #pragma unroll
                    for (int i = 0; i < 4; i++) Cb[(row0 + i) * 1024 + cl] = f2bf(acc[m][n][i]);
                } else {
                    u16* Cb = (u16*)C2;
                    long cl = col - 5120;
                    ushort4 pk;
                    pk.x = f2bf(acc[m][n][0]);
                    pk.y = f2bf(acc[m][n][1]);
                    pk.z = f2bf(acc[m][n][2]);
                    pk.w = f2bf(acc[m][n][3]);
                    *(ushort4*)&Cb[cl * Mm + row0] = pk;
                }
            }
        }
    }
}

// ---------------- 128^2 GEMM (fallback path K/V projections) ----------------
template <int MODE>
__global__ __launch_bounds__(256) void k_gemm_bt(const u16* __restrict__ A, const u16* __restrict__ BT,
                                                 void* __restrict__ Cp, int M, int N, int K) {
    __shared__ u16 As[4096];
    __shared__ u16 Bs[4096];
    int tid = threadIdx.x, lane = tid & 63, wid = tid >> 6;
    int wr = wid >> 1, wc = wid & 1;
    long m0 = (long)blockIdx.y * 128, n0 = (long)blockIdx.x * 128;
    const f32x4 fz = {0.f, 0.f, 0.f, 0.f};
    f32x4 acc[4][4];
    #pragma unroll
    for (int i = 0; i < 4; i++)
        #pragma unroll
        for (int j = 0; j < 4; j++) acc[i][j] = fz;

    const u16* gA = A + (m0 + (tid >> 2)) * K + (tid & 3) * 8;
    const u16* gB = BT + (n0 + (tid >> 2)) * K + (tid & 3) * 8;
    u16* lA0 = As + wid * 512;
    u16* lA1 = As + 2048 + wid * 512;
    u16* lB0 = Bs + wid * 512;
    u16* lB1 = Bs + 2048 + wid * 512;
    int r15 = lane & 15, khalf = (lane >> 4) * 8;
    long rowoff = (long)64 * K;

    for (int kt = 0; kt < K; kt += 32) {
        gld16(gA + kt, lA0);
        gld16(gA + kt + rowoff, lA1);
        gld16(gB + kt, lB0);
        gld16(gB + kt + rowoff, lB1);
        __syncthreads();
        short8 av[4], bv[4];
        #pragma unroll
        for (int f = 0; f < 4; f++) {
            av[f] = *(const short8*)&As[(wr * 64 + f * 16 + r15) * 32 + khalf];
            bv[f] = *(const short8*)&Bs[(wc * 64 + f * 16 + r15) * 32 + khalf];
        }
        #pragma unroll
        for (int i = 0; i < 4; i++)
            #pragma unroll
            for (int j = 0; j < 4; j++)
                acc[i][j] = __builtin_amdgcn_mfma_f32_16x16x32_bf16(av[i], bv[j], acc[i][j], 0, 0, 0);
        __syncthreads();
    }

    int rq = (lane >> 4) * 4;
    #pragma unroll
    for (int mf = 0; mf < 4; mf++) {
        #pragma unroll
        for (int nf = 0; nf < 4; nf++) {
            long row0 = m0 + wr * 64 + mf * 16 + rq;
            long col = n0 + wc * 64 + nf * 16 + r15;
            if (MODE == 1) {
                u16* Cb = (u16*)Cp;
                ushort4 pk;
                pk.x = f2bf(acc[mf][nf][0]);
                pk.y = f2bf(acc[mf][nf][1]);
                pk.z = f2bf(acc[mf][nf][2]);
                pk.w = f2bf(acc[mf][nf][3]);
                *(ushort4*)&Cb[col * M + row0] = pk;
            } else {
                u16* Cb = (u16*)Cp;
                #pragma unroll
                for (int i = 0; i < 4; i++) Cb[(row0 + i) * N + col] = f2bf(acc[mf][nf][i]);
            }
        }
    }
}

// ---------------- fused RMSNorm + RoPE, bf16 in-place ----------------
__global__ __launch_bounds__(256) void k_normrope(u16* __restrict__ buf,
                                                  const float* __restrict__ w, int NH, float oscale) {
    int row = blockIdx.x * 4 + (threadIdx.x >> 6);
    int lane = threadIdx.x & 63;
    long base = (long)row * 128;
    float x1 = bf2f(buf[base + lane]), x2 = bf2f(buf[base + lane + 64]);
    float ss = x1 * x1 + x2 * x2;
    #pragma unroll
    for (int m = 1; m < 64; m <<= 1) ss += __shfl_xor(ss, m);
    float r = rsqrtf(ss * (1.f / 128.f) + 1e-6f);
    float n1 = x1 * r * w[lane], n2 = x2 * r * w[lane + 64];
    int pos = (row / NH) % Ss;
    float invf = exp2f((float)lane * (-19.931568569324174f / 64.f));
    float ang = (float)pos * invf;
    float c = cosf(ang), sn = sinf(ang);
    buf[base + lane] = f2bf((n1 * c - n2 * sn) * oscale);
    buf[base + lane + 64] = f2bf((n2 * c + n1 * sn) * oscale);
}

// ---------------- flash attention, causal-PAIRED q-tiles (round-5 version) ----------------
__global__ __launch_bounds__(256, 2) void k_attn(const u16* __restrict__ Q, const u16* __restrict__ Kb,
                                                 const u16* __restrict__ Vg, u16* __restrict__ O) {
    __shared__ u16 KT[2][64 * 128];
    __shared__ u16 VT[2][128 * 64];
    int tid = threadIdx.x, lane = tid & 63, wid = tid >> 6;
    int b = blockIdx.z;
    int hk = blockIdx.y;
    int h = hk * 4 + wid;
    int pr = blockIdx.x;           // 0..31
    int q0a = pr * 32;
    int q0b = (63 - pr) * 32;
    int c31 = lane & 31, hi5 = lane >> 5;
    int kx16 = (c31 & 15) << 3;
    int kx8 = (c31 & 7) << 3;

    short8 qfa[8], qfb[8];
    {
        const u16* qra = Q + ((long)(b * Ss + q0a + c31) * NQ + h) * Dd + hi5 * 8;
        const u16* qrb = Q + ((long)(b * Ss + q0b + c31) * NQ + h) * Dd + hi5 * 8;
        #pragma unroll
        for (int c = 0; c < 8; c++) {
            qfa[c] = *(const short8*)(qra + c * 16);
            qfb[c] = *(const short8*)(qrb + c * 16);
        }
    }

    const u16* kg[4];
    const u16* vg[4];
    int i0 = wid * 4;
    #pragma unroll
    for (int ii = 0; ii < 4; ii++) {
        int i = i0 + ii;
        int r = i * 4 + (lane >> 4);
        kg[ii] = Kb + ((long)(b * Ss + r) * NKV + hk) * Dd + 8 * ((lane & 15) ^ (r & 15));
        int d = i * 8 + (lane >> 3);
        vg[ii] = Vg + (long)(hk * Dd + d) * Mm + (long)b * Ss + 8 * ((lane & 7) ^ (d & 7));
    }

    f32x16 oaa[4], oab[4];
    #pragma unroll
    for (int f = 0; f < 4; f++)
        #pragma unroll
        for (int r = 0; r < 16; r++) { oaa[f][r] = 0.f; oab[f][r] = 0.f; }
    float mra = -INFINITY, lra = 0.f, mrb = -INFINITY, lrb = 0.f;

    const long kadv = (long)64 * NKV * Dd;
    int nt = q0b / 64 + 1;
    int cur = 0;

    auto STEP = [&](int k0, int q0, const short8 (&qf)[8], f32x16 (&oa)[4],
                    float& mrun, float& lrun) {
        int ql = q0 + c31;
        int krow = k0 & 32;
        f32x16 st;
        #pragma unroll
        for (int r = 0; r < 16; r++) st[r] = 0.f;
        __builtin_amdgcn_s_setprio(1);
        #pragma unroll
        for (int c = 0; c < 8; c++) {
            short8 kf = *(const short8*)&KT[cur][(krow + c31) * 128 + ((c * 16 + hi5 * 8) ^ kx16)];
            st = __builtin_amdgcn_mfma_f32_32x32x16_bf16(kf, qf[c], st, 0, 0, 0);
        }
        __builtin_amdgcn_s_setprio(0);
        float p[16];
        if (k0 + 31 > q0) {
            #pragma unroll
            for (int r = 0; r < 16; r++) {
                int kidx = k0 + (r & 3) + 8 * (r >> 2) + 4 * hi5;
                p[r] = (kidx > ql) ? -INFINITY : st[r];
            }
        } else {
            #pragma unroll
            for (int r = 0; r < 16; r++) p[r] = st[r];
        }
        float pmax = p[0];
        #pragma unroll
        for (int r = 1; r < 16; r++) pmax = fmaxf(pmax, p[r]);
        pmax = fmaxf(pmax, __shfl_xor(pmax, 32));
        if (!__all(pmax - mrun <= 8.f)) {
            float mnew = fmaxf(mrun, pmax);
            float sc = __builtin_amdgcn_exp2f(mrun - mnew);
            lrun *= sc;
            #pragma unroll
            for (int f = 0; f < 4; f++)
                #pragma unroll
                for (int r = 0; r < 16; r++) oa[f][r] *= sc;
            mrun = mnew;
        }
        float ls = 0.f;
        #pragma unroll
        for (int r = 0; r < 16; r++) {
            float e = __builtin_amdgcn_exp2f(p[r] - mrun);
            p[r] = e;
            ls += e;
        }
        ls += __shfl_xor(ls, 32);
        lrun += ls;

        u32 w0 = cvtpk(p[0], p[1]), w1 = cvtpk(p[2], p[3]);
        u32 w2 = cvtpk(p[4], p[5]), w3 = cvtpk(p[6], p[7]);
        u32 w4 = cvtpk(p[8], p[9]), w5 = cvtpk(p[10], p[11]);
        u32 w6 = cvtpk(p[12], p[13]), w7 = cvtpk(p[14], p[15]);
        u32 x0 = (u32)__shfl_xor((int)w0, 32), x1 = (u32)__shfl_xor((int)w1, 32);
        u32 x2 = (u32)__shfl_xor((int)w2, 32), x3 = (u32)__shfl_xor((int)w3, 32);
        u32 x4 = (u32)__shfl_xor((int)w4, 32), x5 = (u32)__shfl_xor((int)w5, 32);
        u32 x6 = (u32)__shfl_xor((int)w6, 32), x7 = (u32)__shfl_xor((int)w7, 32);
        union { u32 u[4]; short8 s; } pb0, pb1;
        if (hi5) {
            pb0.u[0] = x2; pb0.u[1] = x3; pb0.u[2] = w2; pb0.u[3] = w3;
            pb1.u[0] = x6; pb1.u[1] = x7; pb1.u[2] = w6; pb1.u[3] = w7;
        } else {
            pb0.u[0] = w0; pb0.u[1] = w1; pb0.u[2] = x0; pb0.u[3] = x1;
            pb1.u[0] = w4; pb1.u[1] = w5; pb1.u[2] = x4; pb1.u[3] = x5;
        }
        __builtin_amdgcn_s_setprio(1);
        #pragma unroll
        for (int f = 0; f < 4; f++) {
            int d = 32 * f + c31;
            const u16* vrow = &VT[cur][d * 64];
            short8 v0 = *(const short8*)&vrow[(krow + hi5 * 8) ^ kx8];
            short8 v1 = *(const short8*)&vrow[(krow + 16 + hi5 * 8) ^ kx8];
            oa[f] = __builtin_amdgcn_mfma_f32_32x32x16_bf16(v0, pb0.s, oa[f], 0, 0, 0);
            oa[f] = __builtin_amdgcn_mfma_f32_32x32x16_bf16(v1, pb1.s, oa[f], 0, 0, 0);
        }
        __builtin_amdgcn_s_setprio(0);
    };

    #pragma unroll
    for (int ii = 0; ii < 4; ii++) {
        gld16(kg[ii], &KT[0][(i0 + ii) * 512]);
        gld16(vg[ii], &VT[0][(i0 + ii) * 512]);
    }
    __syncthreads();

    for (int t = 0; t < nt; ++t) {
        if (t + 1 < nt) {
            long ko = (long)(t + 1) * kadv;
            int vo = (t + 1) * 64;
            #pragma unroll
            for (int ii = 0; ii < 4; ii++) {
                gld16(kg[ii] + ko, &KT[cur ^ 1][(i0 + ii) * 512]);
                gld16(vg[ii] + vo, &VT[cur ^ 1][(i0 + ii) * 512]);
            }
        }
        #pragma unroll
        for (int ks = 0; ks < 2; ++ks) {
            int k0 = t * 64 + ks * 32;
            if (k0 <= q0a + 31) STEP(k0, q0a, qfa, oaa, mra, lra);
            if (k0 <= q0b + 31) STEP(k0, q0b, qfb, oab, mrb, lrb);
        }
        __syncthreads();
        cur ^= 1;
    }

    #pragma unroll
    for (int x = 0; x < 2; x++) {
        int q0 = x ? q0b : q0a;
        f32x16* oa = x ? oab : oaa;
        float linv = 1.f / (x ? lrb : lra);
        u16* orow = O + ((long)(b * Ss + q0 + c31) * NQ + h) * Dd;
        #pragma unroll
        for (int f = 0; f < 4; f++) {
            #pragma unroll
            for (int rq = 0; rq < 4; rq++) {
                int dbase = 32 * f + 8 * rq + 4 * hi5;
                union { u32 u[2]; ushort4 v; } pk;
                pk.u[0] = cvtpk(oa[f][4 * rq + 0] * linv, oa[f][4 * rq + 1] * linv);
                pk.u[1] = cvtpk(oa[f][4 * rq + 2] * linv, oa[f][4 * rq + 3] * linv);
                *(ushort4*)(orow + dbase) = pk.v;
            }
        }
    }
}

// ---------------- launch ----------------
// Fused layout (needs 128 MB):
//   [  0, 32M): xb   x bf16; dead after QKV GEMM -> reused as ao
//   [ 32, 64M): Wq   wq^T; dead after QKV GEMM -> reused as wo^T
//   [ 64, 96M): qb
//   [ 96,104M): kb
//   [104,112M): vt
//   [112,128M): Wkv  wk^T (rows 0..1023) + wv^T (rows 1024..2047)
// Fallback (112 MB): round-5 layout, W region serially reused.
extern "C" void kernel_launch(void* const* d_in, const int* in_sizes, int n_in,
                              void* d_out, int out_size, void* d_ws, size_t ws_size,
                              hipStream_t stream) {
    (void)in_sizes; (void)n_in; (void)out_size;
    const float* x = (const float*)d_in[0];
    const float* wq = (const float*)d_in[1];
    const float* wk = (const float*)d_in[2];
    const float* wv = (const float*)d_in[3];
    const float* wo = (const float*)d_in[4];
    const float* qnw = (const float*)d_in[5];
    const float* knw = (const float*)d_in[6];

    char* ws = (char*)d_ws;
    const size_t MB = 1024 * 1024;
    const float qscale = (float)(0.08838834764831845 * 1.4426950408889634);

    u16* xb = (u16*)(ws);
    u16* Wq = (u16*)(ws + 32 * MB);
    u16* qb = (u16*)(ws + 64 * MB);
    u16* kb = (u16*)(ws + 96 * MB);
    u16* vt = (u16*)(ws + 104 * MB);
    u16* ao = xb;

    int n4 = Mm * Hh / 4;
    k_cast<<<n4 / 256, 256, 0, stream>>>((const float4*)x, (ushort4*)xb, n4);

    if (ws_size >= 128 * MB) {
        // ---- fused QKV path ----
        u16* Wkv = (u16*)(ws + 112 * MB);
        u16* WkT = Wkv;
        u16* WvT = Wkv + (size_t)1024 * 4096;
        k_transpose<<<dim3(Hh / 32, Hh / 32), 256, 0, stream>>>(wq, Wq, Hh, Hh);
        k_transpose<<<dim3((NKV * Dd) / 32, Hh / 32), 256, 0, stream>>>(wk, WkT, Hh, NKV * Dd);
        k_transpose<<<dim3((NKV * Dd) / 32, Hh / 32), 256, 0, stream>>>(wv, WvT, Hh, NKV * Dd);

        // one GEMM: q (cols 0..4095) -> qb, k (4096..5119) -> kb, v (5120..6143) -> vt^T
        k_gemm256<3><<<dim3(24, Mm / 256), 512, 0, stream>>>(xb, Wq, Wkv, qb, kb, vt, Mm, 6144, Hh);

        k_normrope<<<(Mm * NQ) / 4, 256, 0, stream>>>(qb, qnw, NQ, qscale);
        k_normrope<<<(Mm * NKV) / 4, 256, 0, stream>>>(kb, knw, NKV, 1.0f);
    } else {
        // ---- fallback: round-5 sequence ----
        k_transpose<<<dim3(Hh / 32, Hh / 32), 256, 0, stream>>>(wq, Wq, Hh, Hh);
        k_gemm256<2><<<dim3(Hh / 256, Mm / 256), 512, 0, stream>>>(xb, Wq, nullptr, qb, nullptr, nullptr, Mm, Hh, Hh);
        k_normrope<<<(Mm * NQ) / 4, 256, 0, stream>>>(qb, qnw, NQ, qscale);

        k_transpose<<<dim3((NKV * Dd) / 32, Hh / 32), 256, 0, stream>>>(wk, Wq, Hh, NKV * Dd);
        k_gemm_bt<2><<<dim3((NKV * Dd) / 128, Mm / 128), 256, 0, stream>>>(xb, Wq, kb, Mm, NKV * Dd, Hh);
        k_normrope<<<(Mm * NKV) / 4, 256, 0, stream>>>(kb, knw, NKV, 1.0f);

        k_transpose<<<dim3((NKV * Dd) / 32, Hh / 32), 256, 0, stream>>>(wv, Wq, Hh, NKV * Dd);
        k_gemm_bt<1><<<dim3((NKV * Dd) / 128, Mm / 128), 256, 0, stream>>>(xb, Wq, vt, Mm, NKV * Dd, Hh);
    }

    // attention: paired q-tiles (32*pr, 32*(63-pr)) x 4 q-heads of one kv-head
    k_attn<<<dim3(32, NKV, Bb), 256, 0, stream>>>(qb, kb, vt, ao);

    // output projection -> f32 d_out
    k_transpose<<<dim3(Hh / 32, Hh / 32), 256, 0, stream>>>(wo, Wq, Hh, Hh);
    k_gemm256<0><<<dim3(Hh / 256, Mm / 256), 512, 0, stream>>>(ao, Wq, nullptr, d_out, nullptr, nullptr, Mm, Hh, NQ * Dd);
}